// Round 2
// baseline (2924.292 us; speedup 1.0000x reference)
//
#include <hip/hip_runtime.h>
#include <math.h>

#define B_ 32
#define T_ 128
#define IN_ 128
#define H_ 256
#define OUT_ 128

#define NG 4     // independent batch groups
#define NCB 32   // column blocks per group
#define BPG 8    // batches per group

// ws layout (in float elements)
#define OFF_M2      0         // [256][256]
#define OFF_WCOMBT  65536     // [128][1280]  WcombT[k][c]
#define OFF_BIAS    229376    // [1280]
#define OFF_WCT     230656    // [256][128]
#define OFF_XGT     263424    // [128 t][32 b][1280]  xg(1024)|Bx(256)
#define OFF_HST     5506304   // [4096][256]  CfC h states (row = b*128+t)
#define OFF_HBUF    6554880   // [2][4][8][256] LSTM h double buffer
#define OFF_HCBUF   6571264   // [2][4][8][256] CfC hc double buffer
#define OFF_CNT     6587648   // [4][128] uint barrier counters
#define ZERO_FLOATS (16384 + 16384 + 512)

__device__ __forceinline__ float sigm_f(float x) { return 1.0f / (1.0f + __expf(-x)); }
__device__ __forceinline__ float tanh_f(float x) { return 1.0f - 2.0f / (__expf(2.0f * x) + 1.0f); }

// ---------------- pack: WcombT (W_ih|W_B transposed), bias, W_C^T ----------------
__global__ __launch_bounds__(256) void pack_kernel(
    const float* __restrict__ W_ih, const float* __restrict__ W_B,
    const float* __restrict__ b_ih, const float* __restrict__ b_hh,
    const float* __restrict__ b_B,  const float* __restrict__ W_C,
    float* __restrict__ ws) {
  int idx = blockIdx.x * 256 + threadIdx.x;
  if (idx < 163840) {  // WcombT[k][c]
    int k = idx / 1280, c = idx - k * 1280;
    ws[OFF_WCOMBT + idx] = (c < 1024) ? W_ih[c * 128 + k] : W_B[(c - 1024) * 128 + k];
    return;
  }
  idx -= 163840;
  if (idx < 1280) {
    ws[OFF_BIAS + idx] = (idx < 1024) ? (b_ih[idx] + b_hh[idx]) : b_B[idx - 1024];
    return;
  }
  idx -= 1280;
  if (idx < 32768) {  // W_CT[k][o]
    int k = idx >> 7, o = idx & 127;
    ws[OFF_WCT + idx] = W_C[o * 256 + k];
  }
}

// ---------------- M2 = (W_A D) (W_A D),  D = diag(1/tau) ----------------
__global__ __launch_bounds__(256) void m2_kernel(
    const float* __restrict__ W_A, const float* __restrict__ tau,
    float* __restrict__ M2) {
  __shared__ float adrow[256];  // AD[i][m] = W_A[i][m]/tau[m]
  const int i = blockIdx.x, k = threadIdx.x;
  const float itk = 1.0f / tau[k];
  adrow[k] = W_A[i * 256 + k] * itk;
  __syncthreads();
  float s = 0.f;
#pragma unroll 8
  for (int m = 0; m < 256; ++m)
    s = fmaf(adrow[m], W_A[m * 256 + k], s);
  M2[i * 256 + k] = s * itk;  // = sum_m AD[i][m] * AD[m][k]
}

// ---------------- xg/Bx precompute, layout [t][b][1280] ----------------
__global__ __launch_bounds__(256) void xgt_kernel(
    const float* __restrict__ x, const float* __restrict__ WT,
    const float* __restrict__ bias, float* __restrict__ xgT) {
  __shared__ float xs[8 * 128];
  const int tid = threadIdx.x;
  const int rt = blockIdx.x, ct = blockIdx.y;
  ((float4*)xs)[tid] = ((const float4*)(x + rt * 1024))[tid];
  __syncthreads();
  const int r = tid >> 5, cg = tid & 31;
  const int c0 = ct * 256 + cg * 8;
  const float4* b4 = (const float4*)(bias + c0);
  float4 bA = b4[0], bB = b4[1];
  float a0 = bA.x, a1 = bA.y, a2 = bA.z, a3 = bA.w;
  float a4 = bB.x, a5 = bB.y, a6 = bB.z, a7 = bB.w;
  const float4* xr4 = (const float4*)(xs + r * 128);
#pragma unroll 4
  for (int k4 = 0; k4 < 32; ++k4) {
    float4 xv = xr4[k4];
#define STEPB(kk, comp)                                                      \
    {                                                                        \
      const float4* w = (const float4*)(WT + (k4 * 4 + kk) * 1280 + c0);     \
      float4 wA = w[0], wB = w[1];                                           \
      a0 = fmaf(wA.x, comp, a0); a1 = fmaf(wA.y, comp, a1);                  \
      a2 = fmaf(wA.z, comp, a2); a3 = fmaf(wA.w, comp, a3);                  \
      a4 = fmaf(wB.x, comp, a4); a5 = fmaf(wB.y, comp, a5);                  \
      a6 = fmaf(wB.z, comp, a6); a7 = fmaf(wB.w, comp, a7);                  \
    }
    STEPB(0, xv.x) STEPB(1, xv.y) STEPB(2, xv.z) STEPB(3, xv.w)
#undef STEPB
  }
  const int row = rt * 8 + r;          // row = b*128 + t
  const int bb = row >> 7, tt = row & 127;
  float4* dst = (float4*)(xgT + ((long)(tt * 32 + bb)) * 1280 + c0);
  dst[0] = make_float4(a0, a1, a2, a3);
  dst[1] = make_float4(a4, a5, a6, a7);
}

// ---------------- cooperative recurrence: 128 blocks = 4 groups x 32 col-blocks ----
__global__ __launch_bounds__(256) void recur2_kernel(
    const float* __restrict__ ts_all, const float* __restrict__ tau,
    const float* __restrict__ sigma, const float* __restrict__ W_hh,
    const float* __restrict__ W_A, const float* __restrict__ M2,
    const float* __restrict__ xgT, float* __restrict__ hbuf,
    float* __restrict__ hcbuf, unsigned int* __restrict__ cnt,
    float* __restrict__ hstate) {
  const int g  = blockIdx.x >> 5;
  const int cb = blockIdx.x & 31;
  const int tid = threadIdx.x;
  const int lane = tid & 63, wv = tid >> 6;

  // ---- persistent register weights ----
  // gates: thread (gc = tid&31 -> column, gkq = tid>>5 -> k-range of 32)
  const int gc = tid & 31, gkq = tid >> 5;
  const int grow = (gc >> 3) * 256 + 8 * cb + (gc & 7);
  float wg[32];
  {
    const float4* src = (const float4*)(W_hh + grow * 256 + gkq * 32);
#pragma unroll
    for (int k4 = 0; k4 < 8; ++k4) {
      float4 v = src[k4];
      wg[4 * k4 + 0] = v.x; wg[4 * k4 + 1] = v.y;
      wg[4 * k4 + 2] = v.z; wg[4 * k4 + 3] = v.w;
    }
  }
  // cfc: thread (il = tid&7 -> row i, ckq = tid>>3 -> k'-range of 24)
  const int il = tid & 7, ckq = tid >> 3;
  const int ci = 8 * cb + il;
  const float itau_i = 1.0f / tau[ci];
  float wc[24];
#pragma unroll
  for (int kk = 0; kk < 24; ++kk) {
    int kp = ckq * 24 + kk;
    float v;
    if (kp < 256)      v = W_A[ci * 256 + kp] / tau[kp];
    else if (kp < 512) v = W_A[ci * 256 + (kp - 256)] * itau_i;
    else               v = 0.5f * M2[ci * 256 + (kp - 512)];
    wc[kk] = v;
  }
  // combine-stage constants (mapping: b = tid&7, jj = (tid>>3)&7)
  const float itau_comb = 1.0f / tau[8 * cb + ((tid >> 3) & 7)];

  __shared__ float h_s[8][256];
  __shared__ float hc_s[8][256];
  __shared__ float q_s[8][768];
  __shared__ float redg[4][32][8];
  __shared__ float redc[4][8][8];
  __shared__ float gate_s[32][8];
  __shared__ float cst_s[8][8];   // [jj][b] LSTM cell state
  __shared__ float isig_s[256];
  __shared__ float ts_s[8];
  isig_s[tid] = 1.0f / sigma[tid];
  if (tid < 64) cst_s[tid >> 3][tid & 7] = 0.f;
  __syncthreads();

  for (int t = 0; t < T_; ++t) {
    const int rb = t & 1, wb = rb ^ 1;
    // ---- stage state from global (written by group peers last step) ----
    {
      const float4* hsrc  = (const float4*)(hbuf  + (rb * 4 + g) * 2048);
      const float4* hcsrc = (const float4*)(hcbuf + (rb * 4 + g) * 2048);
      float4* hdst  = (float4*)&h_s[0][0];
      float4* hcdst = (float4*)&hc_s[0][0];
      hdst[tid]        = hsrc[tid];
      hdst[tid + 256]  = hsrc[tid + 256];
      hcdst[tid]       = hcsrc[tid];
      hcdst[tid + 256] = hcsrc[tid + 256];
    }
    // ---- prefetches (consumed after matvecs) ----
    float xgv, bxv = 0.f;
    {
      const int pc = tid >> 3, pb = tid & 7;  // (column, batch) for gate sum stage
      const long base = ((long)t * 32 + g * 8 + pb) * 1280;
      xgv = xgT[base + (pc >> 3) * 256 + 8 * cb + (pc & 7)];
      if (tid < 64) bxv = xgT[base + 1024 + 8 * cb + pc];  // pc = jj here
    }
    if (tid < 8) ts_s[tid] = ts_all[(g * 8 + tid) * T_ + t];
    __syncthreads();

    // ---- q = [ts*hc ; ts*tanh(hc/sigma) ; ts^2*hc] ----
    {
      const int qb = tid >> 5, qk0 = (tid & 31) * 8;
      const float tsb = ts_s[qb], ts2b = tsb * tsb;
#pragma unroll
      for (int kk = 0; kk < 8; ++kk) {
        const int k = qk0 + kk;
        const float hv = hc_s[qb][k];
        q_s[qb][k]       = tsb * hv;
        q_s[qb][256 + k] = tsb * tanh_f(hv * isig_s[k]);
        q_s[qb][512 + k] = ts2b * hv;
      }
    }
    __syncthreads();

    // ---- CfC matvec: acc_c[b] = Gc[i, k'range] . q[b, k'range] ----
    float accc[8];
#pragma unroll
    for (int b = 0; b < 8; ++b) {
      const float4* qp = (const float4*)&q_s[b][ckq * 24];
      float a0 = 0.f, a1 = 0.f;
#pragma unroll
      for (int k4 = 0; k4 < 6; ++k4) {
        float4 qv = qp[k4];
        a0 = fmaf(wc[4 * k4 + 0], qv.x, a0);
        a1 = fmaf(wc[4 * k4 + 1], qv.y, a1);
        a0 = fmaf(wc[4 * k4 + 2], qv.z, a0);
        a1 = fmaf(wc[4 * k4 + 3], qv.w, a1);
      }
      accc[b] = a0 + a1;
    }
    // ---- gates matvec: acc_g[b] = W_hh[grow, krange] . h[b, krange] ----
    float accg[8];
#pragma unroll
    for (int b = 0; b < 8; ++b) {
      const float4* hp = (const float4*)&h_s[b][gkq * 32];
      float a0 = 0.f, a1 = 0.f;
#pragma unroll
      for (int k4 = 0; k4 < 8; ++k4) {
        float4 hv = hp[k4];
        a0 = fmaf(wg[4 * k4 + 0], hv.x, a0);
        a1 = fmaf(wg[4 * k4 + 1], hv.y, a1);
        a0 = fmaf(wg[4 * k4 + 2], hv.z, a0);
        a1 = fmaf(wg[4 * k4 + 3], hv.w, a1);
      }
      accg[b] = a0 + a1;
    }
    // ---- reductions ----
#pragma unroll
    for (int b = 0; b < 8; ++b) accg[b] += __shfl_xor(accg[b], 32);
    if (lane < 32) {
#pragma unroll
      for (int b = 0; b < 8; ++b) redg[wv][lane][b] = accg[b];
    }
#pragma unroll
    for (int b = 0; b < 8; ++b) {
      accc[b] += __shfl_xor(accc[b], 8);
      accc[b] += __shfl_xor(accc[b], 16);
      accc[b] += __shfl_xor(accc[b], 32);
    }
    if (lane < 8) {
#pragma unroll
      for (int b = 0; b < 8; ++b) redc[wv][lane][b] = accc[b];
    }
    __syncthreads();

    // ---- gate totals ----
    {
      const int pc = tid >> 3, pb = tid & 7;
      gate_s[pc][pb] = xgv + redg[0][pc][pb] + redg[1][pc][pb] +
                       redg[2][pc][pb] + redg[3][pc][pb];
    }
    __syncthreads();

    // ---- elementwise LSTM + CfC combine (64 threads: b = tid&7, jj = tid>>3) ----
    if (tid < 64) {
      const int b = tid & 7, jj = tid >> 3;
      const float i_ = sigm_f(gate_s[jj][b]);
      const float f_ = sigm_f(gate_s[8 + jj][b]);
      const float g_ = tanh_f(gate_s[16 + jj][b]);
      const float o_ = sigm_f(gate_s[24 + jj][b]);
      const float cn = fmaf(f_, cst_s[jj][b], i_ * g_);
      cst_s[jj][b] = cn;
      const float ht = o_ * tanh_f(cn);
      const float dot = redc[0][jj][b] + redc[1][jj][b] +
                        redc[2][jj][b] + redc[3][jj][b];
      const float hcold = hc_s[b][8 * cb + jj];
      const float tsb = ts_s[b];
      const float hn = hcold + dot + tsb * bxv * itau_comb + ht;
      const int col = 8 * cb + jj;
      hbuf [(wb * 4 + g) * 2048 + b * 256 + col] = ht;
      hcbuf[(wb * 4 + g) * 2048 + b * 256 + col] = hn;
      hstate[((long)(g * 8 + b) * T_ + t) * 256 + col] = hn;
    }
    __threadfence();     // drain + make stores agent-visible (per wave)
    __syncthreads();
    if (tid == 0) {
      unsigned int* c = &cnt[g * T_ + t];
      __hip_atomic_fetch_add(c, 1u, __ATOMIC_RELEASE, __HIP_MEMORY_SCOPE_AGENT);
      while (__hip_atomic_load(c, __ATOMIC_ACQUIRE, __HIP_MEMORY_SCOPE_AGENT) < NCB)
        __builtin_amdgcn_s_sleep(2);
    }
    __syncthreads();
    __builtin_amdgcn_fence(__ATOMIC_ACQUIRE, "agent");
  }
}

// ---------------- y = hstate @ W_C^T + b_C ----------------
__global__ __launch_bounds__(256) void out_kernel(
    const float* __restrict__ hstate, const float* __restrict__ WCT,
    const float* __restrict__ bC, float* __restrict__ y) {
  __shared__ float hs[16 * 256];
  const int tid = threadIdx.x;
  const long base = (long)blockIdx.x * 16 * 256;
#pragma unroll
  for (int v = 0; v < 4; ++v)
    ((float4*)hs)[tid + v * 256] = ((const float4*)(hstate + base))[tid + v * 256];
  __syncthreads();
  const int r = tid >> 4, cg = tid & 15;
  const int c0 = cg * 8;
  const float4* b4 = (const float4*)(bC + c0);
  float4 bA = b4[0], bB = b4[1];
  float a0 = bA.x, a1 = bA.y, a2 = bA.z, a3 = bA.w;
  float a4 = bB.x, a5 = bB.y, a6 = bB.z, a7 = bB.w;
  const float4* hr4 = (const float4*)(hs + r * 256);
#pragma unroll 4
  for (int k4 = 0; k4 < 64; ++k4) {
    float4 hv = hr4[k4];
#define STEPD(kk, comp)                                                     \
    {                                                                       \
      const float4* w = (const float4*)(WCT + (k4 * 4 + kk) * 128 + c0);    \
      float4 wA = w[0], wB = w[1];                                          \
      a0 = fmaf(wA.x, comp, a0); a1 = fmaf(wA.y, comp, a1);                 \
      a2 = fmaf(wA.z, comp, a2); a3 = fmaf(wA.w, comp, a3);                 \
      a4 = fmaf(wB.x, comp, a4); a5 = fmaf(wB.y, comp, a5);                 \
      a6 = fmaf(wB.z, comp, a6); a7 = fmaf(wB.w, comp, a7);                 \
    }
    STEPD(0, hv.x) STEPD(1, hv.y) STEPD(2, hv.z) STEPD(3, hv.w)
#undef STEPD
  }
  const int row = blockIdx.x * 16 + r;
  float4* dst = (float4*)(y + (long)row * 128 + c0);
  dst[0] = make_float4(a0, a1, a2, a3);
  dst[1] = make_float4(a4, a5, a6, a7);
}

extern "C" void kernel_launch(void* const* d_in, const int* in_sizes, int n_in,
                              void* d_out, int out_size, void* d_ws, size_t ws_size,
                              hipStream_t stream) {
  const float* x     = (const float*)d_in[0];
  const float* tspan = (const float*)d_in[1];
  const float* tau   = (const float*)d_in[2];
  const float* sigma = (const float*)d_in[3];
  const float* W_A   = (const float*)d_in[4];
  const float* W_B   = (const float*)d_in[5];
  const float* b_B   = (const float*)d_in[6];
  const float* W_C   = (const float*)d_in[7];
  const float* b_C   = (const float*)d_in[8];
  const float* W_ih  = (const float*)d_in[9];
  const float* W_hh  = (const float*)d_in[10];
  const float* b_ih  = (const float*)d_in[11];
  const float* b_hh  = (const float*)d_in[12];
  float* ws = (float*)d_ws;
  float* y = (float*)d_out;

  hipMemsetAsync(ws + OFF_HBUF, 0, (size_t)ZERO_FLOATS * sizeof(float), stream);
  pack_kernel<<<774, 256, 0, stream>>>(W_ih, W_B, b_ih, b_hh, b_B, W_C, ws);
  m2_kernel<<<256, 256, 0, stream>>>(W_A, tau, ws + OFF_M2);
  xgt_kernel<<<dim3(512, 5), 256, 0, stream>>>(x, ws + OFF_WCOMBT, ws + OFF_BIAS,
                                               ws + OFF_XGT);
  recur2_kernel<<<NG * NCB, 256, 0, stream>>>(
      tspan, tau, sigma, W_hh, W_A, ws + OFF_M2, ws + OFF_XGT,
      ws + OFF_HBUF, ws + OFF_HCBUF, (unsigned int*)(ws + OFF_CNT),
      ws + OFF_HST);
  out_kernel<<<256, 256, 0, stream>>>(ws + OFF_HST, ws + OFF_WCT, b_C, y);
}

// Round 3
// 1109.540 us; speedup vs baseline: 2.6356x; 2.6356x over previous
//
#include <hip/hip_runtime.h>
#include <math.h>

#define B_ 32
#define T_ 128
#define IN_ 128
#define H_ 256
#define OUT_ 128

#define NG 4     // independent batch groups
#define NCB 32   // column blocks per group
#define BPG 8    // batches per group

// ws layout (in float elements)
#define OFF_M2      0         // [256][256]
#define OFF_WCOMBT  65536     // [128][1280]  WcombT[k][c]
#define OFF_BIAS    229376    // [1280]
#define OFF_WCT     230656    // [256][128]
#define OFF_XGT     263424    // [128 t][32 b][1280]  xg(1024)|Bx(256)
#define OFF_HST     5506304   // [4096][256]  CfC h states (row = b*128+t)
#define OFF_HBUF    6554880   // [2][4][8][256] LSTM h double buffer
#define OFF_HCBUF   6571264   // [2][4][8][256] CfC hc double buffer
#define OFF_CNT     6587648   // [4][128] uint barrier counters
#define ZERO_FLOATS (16384 + 16384 + 512)

__device__ __forceinline__ float sigm_f(float x) { return 1.0f / (1.0f + __expf(-x)); }
__device__ __forceinline__ float tanh_f(float x) { return 1.0f - 2.0f / (__expf(2.0f * x) + 1.0f); }

// coherent (agent-scope, relaxed) helpers: per-op coherence, NO cache maintenance
__device__ __forceinline__ float2 cload_f2(const float* p) {
  unsigned long long u = __hip_atomic_load((const unsigned long long*)p,
                                           __ATOMIC_RELAXED, __HIP_MEMORY_SCOPE_AGENT);
  union { unsigned long long u; float2 f; } cv; cv.u = u;
  return cv.f;
}
__device__ __forceinline__ void cstore_f(float* p, float v) {
  __hip_atomic_store(p, v, __ATOMIC_RELAXED, __HIP_MEMORY_SCOPE_AGENT);
}

// ---------------- pack: WcombT (W_ih|W_B transposed), bias, W_C^T ----------------
__global__ __launch_bounds__(256) void pack_kernel(
    const float* __restrict__ W_ih, const float* __restrict__ W_B,
    const float* __restrict__ b_ih, const float* __restrict__ b_hh,
    const float* __restrict__ b_B,  const float* __restrict__ W_C,
    float* __restrict__ ws) {
  int idx = blockIdx.x * 256 + threadIdx.x;
  if (idx < 163840) {  // WcombT[k][c]
    int k = idx / 1280, c = idx - k * 1280;
    ws[OFF_WCOMBT + idx] = (c < 1024) ? W_ih[c * 128 + k] : W_B[(c - 1024) * 128 + k];
    return;
  }
  idx -= 163840;
  if (idx < 1280) {
    ws[OFF_BIAS + idx] = (idx < 1024) ? (b_ih[idx] + b_hh[idx]) : b_B[idx - 1024];
    return;
  }
  idx -= 1280;
  if (idx < 32768) {  // W_CT[k][o]
    int k = idx >> 7, o = idx & 127;
    ws[OFF_WCT + idx] = W_C[o * 256 + k];
  }
}

// ---------------- M2 = (W_A D) (W_A D),  D = diag(1/tau) ----------------
__global__ __launch_bounds__(256) void m2_kernel(
    const float* __restrict__ W_A, const float* __restrict__ tau,
    float* __restrict__ M2) {
  __shared__ float adrow[256];  // AD[i][m] = W_A[i][m]/tau[m]
  const int i = blockIdx.x, k = threadIdx.x;
  const float itk = 1.0f / tau[k];
  adrow[k] = W_A[i * 256 + k] * itk;
  __syncthreads();
  float s = 0.f;
#pragma unroll 8
  for (int m = 0; m < 256; ++m)
    s = fmaf(adrow[m], W_A[m * 256 + k], s);
  M2[i * 256 + k] = s * itk;  // = sum_m AD[i][m] * AD[m][k]
}

// ---------------- xg/Bx precompute, layout [t][b][1280] ----------------
__global__ __launch_bounds__(256) void xgt_kernel(
    const float* __restrict__ x, const float* __restrict__ WT,
    const float* __restrict__ bias, float* __restrict__ xgT) {
  __shared__ float xs[8 * 128];
  const int tid = threadIdx.x;
  const int rt = blockIdx.x, ct = blockIdx.y;
  ((float4*)xs)[tid] = ((const float4*)(x + rt * 1024))[tid];
  __syncthreads();
  const int r = tid >> 5, cg = tid & 31;
  const int c0 = ct * 256 + cg * 8;
  const float4* b4 = (const float4*)(bias + c0);
  float4 bA = b4[0], bB = b4[1];
  float a0 = bA.x, a1 = bA.y, a2 = bA.z, a3 = bA.w;
  float a4 = bB.x, a5 = bB.y, a6 = bB.z, a7 = bB.w;
  const float4* xr4 = (const float4*)(xs + r * 128);
#pragma unroll 4
  for (int k4 = 0; k4 < 32; ++k4) {
    float4 xv = xr4[k4];
#define STEPB(kk, comp)                                                      \
    {                                                                        \
      const float4* w = (const float4*)(WT + (k4 * 4 + kk) * 1280 + c0);     \
      float4 wA = w[0], wB = w[1];                                           \
      a0 = fmaf(wA.x, comp, a0); a1 = fmaf(wA.y, comp, a1);                  \
      a2 = fmaf(wA.z, comp, a2); a3 = fmaf(wA.w, comp, a3);                  \
      a4 = fmaf(wB.x, comp, a4); a5 = fmaf(wB.y, comp, a5);                  \
      a6 = fmaf(wB.z, comp, a6); a7 = fmaf(wB.w, comp, a7);                  \
    }
    STEPB(0, xv.x) STEPB(1, xv.y) STEPB(2, xv.z) STEPB(3, xv.w)
#undef STEPB
  }
  const int row = rt * 8 + r;          // row = b*128 + t
  const int bb = row >> 7, tt = row & 127;
  float4* dst = (float4*)(xgT + ((long)(tt * 32 + bb)) * 1280 + c0);
  dst[0] = make_float4(a0, a1, a2, a3);
  dst[1] = make_float4(a4, a5, a6, a7);
}

// ---------------- cooperative recurrence: 128 blocks = 4 groups x 32 col-blocks ----
__global__ __launch_bounds__(256) void recur2_kernel(
    const float* __restrict__ ts_all, const float* __restrict__ tau,
    const float* __restrict__ sigma, const float* __restrict__ W_hh,
    const float* __restrict__ W_A, const float* __restrict__ M2,
    const float* __restrict__ xgT, float* __restrict__ hbuf,
    float* __restrict__ hcbuf, unsigned int* __restrict__ cnt,
    float* __restrict__ hstate) {
  const int g  = blockIdx.x >> 5;
  const int cb = blockIdx.x & 31;
  const int tid = threadIdx.x;
  const int lane = tid & 63, wv = tid >> 6;

  // ---- persistent register weights ----
  const int gc = tid & 31, gkq = tid >> 5;
  const int grow = (gc >> 3) * 256 + 8 * cb + (gc & 7);
  float wg[32];
  {
    const float4* src = (const float4*)(W_hh + grow * 256 + gkq * 32);
#pragma unroll
    for (int k4 = 0; k4 < 8; ++k4) {
      float4 v = src[k4];
      wg[4 * k4 + 0] = v.x; wg[4 * k4 + 1] = v.y;
      wg[4 * k4 + 2] = v.z; wg[4 * k4 + 3] = v.w;
    }
  }
  const int il = tid & 7, ckq = tid >> 3;
  const int ci = 8 * cb + il;
  const float itau_i = 1.0f / tau[ci];
  float wc[24];
#pragma unroll
  for (int kk = 0; kk < 24; ++kk) {
    int kp = ckq * 24 + kk;
    float v;
    if (kp < 256)      v = W_A[ci * 256 + kp] / tau[kp];
    else if (kp < 512) v = W_A[ci * 256 + (kp - 256)] * itau_i;
    else               v = 0.5f * M2[ci * 256 + (kp - 512)];
    wc[kk] = v;
  }
  const float itau_comb = 1.0f / tau[8 * cb + ((tid >> 3) & 7)];

  __shared__ float h_s[8][256];
  __shared__ float hc_s[8][256];
  __shared__ float q_s[8][768];
  __shared__ float redg[4][32][8];
  __shared__ float redc[4][8][8];
  __shared__ float gate_s[32][8];
  __shared__ float cst_s[8][8];
  __shared__ float isig_s[256];
  __shared__ float ts_s[8];
  isig_s[tid] = 1.0f / sigma[tid];
  if (tid < 64) cst_s[tid >> 3][tid & 7] = 0.f;
  __syncthreads();

  for (int t = 0; t < T_; ++t) {
    const int rb = t & 1, wb = rb ^ 1;
    // ---- stage state from coherence point (written by group peers last step) ----
    {
      const float* hsrc  = hbuf  + (rb * 4 + g) * 2048;
      const float* hcsrc = hcbuf + (rb * 4 + g) * 2048;
      float2* hdst  = (float2*)&h_s[0][0];
      float2* hcdst = (float2*)&hc_s[0][0];
#pragma unroll
      for (int v = 0; v < 4; ++v) {
        hdst[v * 256 + tid]  = cload_f2(hsrc  + (v * 256 + tid) * 2);
        hcdst[v * 256 + tid] = cload_f2(hcsrc + (v * 256 + tid) * 2);
      }
    }
    // ---- prefetches (plain cached loads; L2 stays warm — no invalidates) ----
    float xgv, bxv = 0.f;
    {
      const int pc = tid >> 3, pb = tid & 7;
      const long base = ((long)t * 32 + g * 8 + pb) * 1280;
      xgv = xgT[base + (pc >> 3) * 256 + 8 * cb + (pc & 7)];
      if (tid < 64) bxv = xgT[base + 1024 + 8 * cb + pc];
    }
    if (tid < 8) ts_s[tid] = ts_all[(g * 8 + tid) * T_ + t];
    __syncthreads();

    // ---- q = [ts*hc ; ts*tanh(hc/sigma) ; ts^2*hc] ----
    {
      const int qb = tid >> 5, qk0 = (tid & 31) * 8;
      const float tsb = ts_s[qb], ts2b = tsb * tsb;
#pragma unroll
      for (int kk = 0; kk < 8; ++kk) {
        const int k = qk0 + kk;
        const float hv = hc_s[qb][k];
        q_s[qb][k]       = tsb * hv;
        q_s[qb][256 + k] = tsb * tanh_f(hv * isig_s[k]);
        q_s[qb][512 + k] = ts2b * hv;
      }
    }
    __syncthreads();

    // ---- CfC matvec ----
    float accc[8];
#pragma unroll
    for (int b = 0; b < 8; ++b) {
      const float4* qp = (const float4*)&q_s[b][ckq * 24];
      float a0 = 0.f, a1 = 0.f;
#pragma unroll
      for (int k4 = 0; k4 < 6; ++k4) {
        float4 qv = qp[k4];
        a0 = fmaf(wc[4 * k4 + 0], qv.x, a0);
        a1 = fmaf(wc[4 * k4 + 1], qv.y, a1);
        a0 = fmaf(wc[4 * k4 + 2], qv.z, a0);
        a1 = fmaf(wc[4 * k4 + 3], qv.w, a1);
      }
      accc[b] = a0 + a1;
    }
    // ---- gates matvec ----
    float accg[8];
#pragma unroll
    for (int b = 0; b < 8; ++b) {
      const float4* hp = (const float4*)&h_s[b][gkq * 32];
      float a0 = 0.f, a1 = 0.f;
#pragma unroll
      for (int k4 = 0; k4 < 8; ++k4) {
        float4 hv = hp[k4];
        a0 = fmaf(wg[4 * k4 + 0], hv.x, a0);
        a1 = fmaf(wg[4 * k4 + 1], hv.y, a1);
        a0 = fmaf(wg[4 * k4 + 2], hv.z, a0);
        a1 = fmaf(wg[4 * k4 + 3], hv.w, a1);
      }
      accg[b] = a0 + a1;
    }
    // ---- reductions ----
#pragma unroll
    for (int b = 0; b < 8; ++b) accg[b] += __shfl_xor(accg[b], 32);
    if (lane < 32) {
#pragma unroll
      for (int b = 0; b < 8; ++b) redg[wv][lane][b] = accg[b];
    }
#pragma unroll
    for (int b = 0; b < 8; ++b) {
      accc[b] += __shfl_xor(accc[b], 8);
      accc[b] += __shfl_xor(accc[b], 16);
      accc[b] += __shfl_xor(accc[b], 32);
    }
    if (lane < 8) {
#pragma unroll
      for (int b = 0; b < 8; ++b) redc[wv][lane][b] = accc[b];
    }
    __syncthreads();

    // ---- gate totals ----
    {
      const int pc = tid >> 3, pb = tid & 7;
      gate_s[pc][pb] = xgv + redg[0][pc][pb] + redg[1][pc][pb] +
                       redg[2][pc][pb] + redg[3][pc][pb];
    }
    __syncthreads();

    // ---- elementwise LSTM + CfC combine (wave 0: b = tid&7, jj = tid>>3) ----
    if (tid < 64) {
      const int b = tid & 7, jj = tid >> 3;
      const float i_ = sigm_f(gate_s[jj][b]);
      const float f_ = sigm_f(gate_s[8 + jj][b]);
      const float g_ = tanh_f(gate_s[16 + jj][b]);
      const float o_ = sigm_f(gate_s[24 + jj][b]);
      const float cn = fmaf(f_, cst_s[jj][b], i_ * g_);
      cst_s[jj][b] = cn;
      const float ht = o_ * tanh_f(cn);
      const float dot = redc[0][jj][b] + redc[1][jj][b] +
                        redc[2][jj][b] + redc[3][jj][b];
      const float hcold = hc_s[b][8 * cb + jj];
      const float tsb = ts_s[b];
      const float hn = hcold + dot + tsb * bxv * itau_comb + ht;
      const int col = 8 * cb + jj;
      cstore_f(hbuf  + (wb * 4 + g) * 2048 + b * 256 + col, ht);
      cstore_f(hcbuf + (wb * 4 + g) * 2048 + b * 256 + col, hn);
      hstate[((long)(g * 8 + b) * T_ + t) * 256 + col] = hn;  // plain (next kernel)
    }
    // ---- barrier: waitcnt + relaxed add + relaxed poll; NO cache maintenance ----
    if (tid == 0) {
      unsigned int* c = &cnt[g * T_ + t];
      asm volatile("s_waitcnt vmcnt(0)" ::: "memory");
      __hip_atomic_fetch_add(c, 1u, __ATOMIC_RELAXED, __HIP_MEMORY_SCOPE_AGENT);
      while (__hip_atomic_load(c, __ATOMIC_RELAXED, __HIP_MEMORY_SCOPE_AGENT) < NCB) {
        __builtin_amdgcn_s_sleep(1);
      }
    }
    __syncthreads();
  }
}

// ---------------- y = hstate @ W_C^T + b_C ----------------
__global__ __launch_bounds__(256) void out_kernel(
    const float* __restrict__ hstate, const float* __restrict__ WCT,
    const float* __restrict__ bC, float* __restrict__ y) {
  __shared__ float hs[16 * 256];
  const int tid = threadIdx.x;
  const long base = (long)blockIdx.x * 16 * 256;
#pragma unroll
  for (int v = 0; v < 4; ++v)
    ((float4*)hs)[tid + v * 256] = ((const float4*)(hstate + base))[tid + v * 256];
  __syncthreads();
  const int r = tid >> 4, cg = tid & 15;
  const int c0 = cg * 8;
  const float4* b4 = (const float4*)(bC + c0);
  float4 bA = b4[0], bB = b4[1];
  float a0 = bA.x, a1 = bA.y, a2 = bA.z, a3 = bA.w;
  float a4 = bB.x, a5 = bB.y, a6 = bB.z, a7 = bB.w;
  const float4* hr4 = (const float4*)(hs + r * 256);
#pragma unroll 4
  for (int k4 = 0; k4 < 64; ++k4) {
    float4 hv = hr4[k4];
#define STEPD(kk, comp)                                                     \
    {                                                                       \
      const float4* w = (const float4*)(WCT + (k4 * 4 + kk) * 128 + c0);    \
      float4 wA = w[0], wB = w[1];                                          \
      a0 = fmaf(wA.x, comp, a0); a1 = fmaf(wA.y, comp, a1);                 \
      a2 = fmaf(wA.z, comp, a2); a3 = fmaf(wA.w, comp, a3);                 \
      a4 = fmaf(wB.x, comp, a4); a5 = fmaf(wB.y, comp, a5);                 \
      a6 = fmaf(wB.z, comp, a6); a7 = fmaf(wB.w, comp, a7);                 \
    }
    STEPD(0, hv.x) STEPD(1, hv.y) STEPD(2, hv.z) STEPD(3, hv.w)
#undef STEPD
  }
  const int row = blockIdx.x * 16 + r;
  float4* dst = (float4*)(y + (long)row * 128 + c0);
  dst[0] = make_float4(a0, a1, a2, a3);
  dst[1] = make_float4(a4, a5, a6, a7);
}

extern "C" void kernel_launch(void* const* d_in, const int* in_sizes, int n_in,
                              void* d_out, int out_size, void* d_ws, size_t ws_size,
                              hipStream_t stream) {
  const float* x     = (const float*)d_in[0];
  const float* tspan = (const float*)d_in[1];
  const float* tau   = (const float*)d_in[2];
  const float* sigma = (const float*)d_in[3];
  const float* W_A   = (const float*)d_in[4];
  const float* W_B   = (const float*)d_in[5];
  const float* b_B   = (const float*)d_in[6];
  const float* W_C   = (const float*)d_in[7];
  const float* b_C   = (const float*)d_in[8];
  const float* W_ih  = (const float*)d_in[9];
  const float* W_hh  = (const float*)d_in[10];
  const float* b_ih  = (const float*)d_in[11];
  const float* b_hh  = (const float*)d_in[12];
  float* ws = (float*)d_ws;
  float* y = (float*)d_out;

  hipMemsetAsync(ws + OFF_HBUF, 0, (size_t)ZERO_FLOATS * sizeof(float), stream);
  pack_kernel<<<774, 256, 0, stream>>>(W_ih, W_B, b_ih, b_hh, b_B, W_C, ws);
  m2_kernel<<<256, 256, 0, stream>>>(W_A, tau, ws + OFF_M2);
  xgt_kernel<<<dim3(512, 5), 256, 0, stream>>>(x, ws + OFF_WCOMBT, ws + OFF_BIAS,
                                               ws + OFF_XGT);
  recur2_kernel<<<NG * NCB, 256, 0, stream>>>(
      tspan, tau, sigma, W_hh, W_A, ws + OFF_M2, ws + OFF_XGT,
      ws + OFF_HBUF, ws + OFF_HCBUF, (unsigned int*)(ws + OFF_CNT),
      ws + OFF_HST);
  out_kernel<<<256, 256, 0, stream>>>(ws + OFF_HST, ws + OFF_WCT, b_C, y);
}

// Round 4
// 1072.084 us; speedup vs baseline: 2.7277x; 1.0349x over previous
//
#include <hip/hip_runtime.h>
#include <math.h>

#define T_ 128
#define NG 4
#define BPG 8

// ws offsets (floats)
#define OFF_M2      0         // [256][256]
#define OFF_WCOMBT  65536     // [128][1280]
#define OFF_BIAS    229376    // [1280]
#define OFF_WCT     230656    // [256][128]
#define OFF_XG2     263424    // [128 t][4 g][32 cb][32 lc][8 b] = 4194304
#define OFF_BX2     4457728   // [128 t][4 g][256 col][8 b]      = 1048576
#define OFF_HSEQ    5506304   // [128 t][4 g][8 b][256]          = 1048576
#define OFF_HCSEQ   6554880   // [128 t][4 g][8 b][256]          = 1048576
// total 7603456 floats = 30.4 MB

#define SENTB 0xFFFFFFFFu

__device__ __forceinline__ float sigm_f(float x) { return 1.0f / (1.0f + __expf(-x)); }
__device__ __forceinline__ float tanh_f(float x) { return 1.0f - 2.0f / (__expf(2.0f * x) + 1.0f); }

__device__ __forceinline__ unsigned long long aload_u64(const unsigned long long* p) {
  return __hip_atomic_load(p, __ATOMIC_RELAXED, __HIP_MEMORY_SCOPE_AGENT);
}
__device__ __forceinline__ void astore_f(float* p, float v) {
  __hip_atomic_store(p, v, __ATOMIC_RELAXED, __HIP_MEMORY_SCOPE_AGENT);
}

// ---------------- pack: WcombT, bias, W_C^T, sentinel fill ----------------
__global__ __launch_bounds__(256) void pack_kernel(
    const float* __restrict__ W_ih, const float* __restrict__ W_B,
    const float* __restrict__ b_ih, const float* __restrict__ b_hh,
    const float* __restrict__ b_B,  const float* __restrict__ W_C,
    float* __restrict__ ws) {
  int idx = blockIdx.x * 256 + threadIdx.x;
  if (idx < 163840) {  // WcombT[k][c]
    int k = idx / 1280, c = idx - k * 1280;
    ws[OFF_WCOMBT + idx] = (c < 1024) ? W_ih[c * 128 + k] : W_B[(c - 1024) * 128 + k];
    return;
  }
  idx -= 163840;
  if (idx < 1280) {
    ws[OFF_BIAS + idx] = (idx < 1024) ? (b_ih[idx] + b_hh[idx]) : b_B[idx - 1024];
    return;
  }
  idx -= 1280;
  if (idx < 32768) {  // W_CT[k][o]
    int k = idx >> 7, o = idx & 127;
    ws[OFF_WCT + idx] = W_C[o * 256 + k];
    return;
  }
  idx -= 32768;
  if (idx < 1048576) {  // sentinel fill of hseq+hcseq via the SAME sc1 path as data
    unsigned long long* p = (unsigned long long*)(ws + OFF_HSEQ);
    __hip_atomic_store(p + idx, 0xFFFFFFFFFFFFFFFFull,
                       __ATOMIC_RELAXED, __HIP_MEMORY_SCOPE_AGENT);
  }
}

// ---------------- M2 = (W_A D)(W_A D), D = diag(1/tau) ----------------
__global__ __launch_bounds__(256) void m2_kernel(
    const float* __restrict__ W_A, const float* __restrict__ tau,
    float* __restrict__ M2) {
  __shared__ float adrow[256];
  const int i = blockIdx.x, k = threadIdx.x;
  const float itk = 1.0f / tau[k];
  adrow[k] = W_A[i * 256 + k] * itk;
  __syncthreads();
  float s = 0.f;
#pragma unroll 8
  for (int m = 0; m < 256; ++m)
    s = fmaf(adrow[m], W_A[m * 256 + k], s);
  M2[i * 256 + k] = s * itk;
}

// ---------------- xg/Bx precompute, scattered into recur-native layout ----------------
__global__ __launch_bounds__(256) void xgt_kernel(
    const float* __restrict__ x, const float* __restrict__ WT,
    const float* __restrict__ bias, float* __restrict__ xg2,
    float* __restrict__ bx2) {
  __shared__ float xs[8 * 128];
  const int tid = threadIdx.x;
  const int rt = blockIdx.x, ct = blockIdx.y;
  ((float4*)xs)[tid] = ((const float4*)(x + rt * 1024))[tid];
  __syncthreads();
  const int r = tid >> 5, cg = tid & 31;
  const int c0 = ct * 256 + cg * 8;
  const float4* b4 = (const float4*)(bias + c0);
  float4 bA = b4[0], bB = b4[1];
  float a[8] = {bA.x, bA.y, bA.z, bA.w, bB.x, bB.y, bB.z, bB.w};
  const float4* xr4 = (const float4*)(xs + r * 128);
#pragma unroll 4
  for (int k4 = 0; k4 < 32; ++k4) {
    float4 xv = xr4[k4];
#define STEPB(kk, comp)                                                      \
    {                                                                        \
      const float4* w = (const float4*)(WT + (k4 * 4 + kk) * 1280 + c0);     \
      float4 wA = w[0], wB = w[1];                                           \
      a[0] = fmaf(wA.x, comp, a[0]); a[1] = fmaf(wA.y, comp, a[1]);          \
      a[2] = fmaf(wA.z, comp, a[2]); a[3] = fmaf(wA.w, comp, a[3]);          \
      a[4] = fmaf(wB.x, comp, a[4]); a[5] = fmaf(wB.y, comp, a[5]);          \
      a[6] = fmaf(wB.z, comp, a[6]); a[7] = fmaf(wB.w, comp, a[7]);          \
    }
    STEPB(0, xv.x) STEPB(1, xv.y) STEPB(2, xv.z) STEPB(3, xv.w)
#undef STEPB
  }
  const int row = rt * 8 + r;          // = b*128 + t
  const int b = row >> 7, t = row & 127;
  const int g = b >> 3, bl = b & 7;
  if (ct < 4) {
    // lc = ct*8 + i, cb = cg : idx = (((t*4+g)*32 + cb)*32 + lc)*8 + bl
    const size_t base = ((size_t)((t * 4 + g) * 32 + cg)) * 256 + ct * 64 + bl;
#pragma unroll
    for (int i = 0; i < 8; ++i) xg2[base + i * 8] = a[i];
  } else {
    const size_t base = ((size_t)(t * 4 + g) * 256 + cg * 8) * 8 + bl;
#pragma unroll
    for (int i = 0; i < 8; ++i) bx2[base + i * 8] = a[i];
  }
}

// ---------------- recurrence: 128 blocks, sentinel dataflow, no barrier ----------------
__global__ __launch_bounds__(256) void recur3_kernel(
    const float* __restrict__ ts_all, const float* __restrict__ tau,
    const float* __restrict__ sigma, const float* __restrict__ W_hh,
    const float* __restrict__ W_A, const float* __restrict__ M2,
    const float* __restrict__ xg2, const float* __restrict__ bx2,
    float* __restrict__ hseq, float* __restrict__ hcseq) {
  const int g = blockIdx.x >> 5, cb = blockIdx.x & 31;
  const int tid = threadIdx.x;

  // ---- gates weights: 16 colgroups x 16 kq; 2 cols/thread, 16 k each ----
  const int kq = tid & 15, cg = tid >> 4;
  float wg[2][16];
#pragma unroll
  for (int c = 0; c < 2; ++c) {
    const int lc = 2 * cg + c;
    const int grow = (lc >> 3) * 256 + 8 * cb + (lc & 7);
    const float4* src = (const float4*)(W_hh + grow * 256 + kq * 16);
#pragma unroll
    for (int k4 = 0; k4 < 4; ++k4) {
      float4 v = src[k4];
      wg[c][4 * k4 + 0] = v.x; wg[c][4 * k4 + 1] = v.y;
      wg[c][4 * k4 + 2] = v.z; wg[c][4 * k4 + 3] = v.w;
    }
  }
  // ---- cfc weights: wave wv covers rows {2wv,2wv+1}; k' = 2*kq6 + 128j + e ----
  const int wv = tid >> 6, kq6 = tid & 63;
  float wc[2][12];
#pragma unroll
  for (int r = 0; r < 2; ++r) {
    const int ci = 8 * cb + 2 * wv + r;
    const float it_i = 1.0f / tau[ci];
#pragma unroll
    for (int j = 0; j < 6; ++j) {
#pragma unroll
      for (int e = 0; e < 2; ++e) {
        const int kp = 2 * kq6 + 128 * j + e;
        float v;
        if (kp < 256)      v = W_A[ci * 256 + kp] / tau[kp];
        else if (kp < 512) v = W_A[ci * 256 + (kp - 256)] * it_i;
        else               v = 0.5f * M2[ci * 256 + (kp - 512)];
        wc[r][2 * j + e] = v;
      }
    }
  }
  const float itau_comb = 1.0f / tau[8 * cb + ((tid >> 3) & 7)];

  __shared__ float h_s[8][256];
  __shared__ float hc_s[8][256];
  __shared__ float q_s[8][768];
  __shared__ float xg_s[256];
  __shared__ float gdot_s[256];   // [lc*8+b]
  __shared__ float cfc_s[8][8];   // [row][b]
  __shared__ float cst_s[64];     // [jj*8+b]
  __shared__ float isig_s[256];
  __shared__ float ts_s[8];
  isig_s[tid] = 1.0f / sigma[tid];
  if (tid < 64) cst_s[tid] = 0.f;
  __syncthreads();

  const unsigned long long* hsq  = (const unsigned long long*)hseq;
  const unsigned long long* hcsq = (const unsigned long long*)hcseq;

  for (int t = 0; t < T_; ++t) {
    // ======== Stage A: prefetch + stage state + build q (fused) ========
    xg_s[tid] = xg2[((size_t)((t * 4 + g) * 32 + cb)) * 256 + tid];
    float bxv = 0.f;
    if (tid < 64)
      bxv = bx2[((size_t)(t * 4 + g) * 256 + 8 * cb) * 8 + tid];
    if (tid < 8) ts_s[tid] = ts_all[(g * 8 + tid) * T_ + t];

    if (t == 0) {
      const float2 z = make_float2(0.f, 0.f);
#pragma unroll
      for (int v = 0; v < 4; ++v) {
        const int flat = v * 256 + tid, b = flat >> 7, k2 = flat & 127;
        ((float2*)&h_s[b][0])[k2] = z;
        ((float2*)&hc_s[b][0])[k2] = z;
        float2* qrow = (float2*)&q_s[b][0];
        qrow[k2] = z; qrow[128 + k2] = z; qrow[256 + k2] = z;
      }
    } else {
      const unsigned long long* hp  = hsq  + (size_t)((t - 1) * 4 + g) * 1024;
      const unsigned long long* hcp = hcsq + (size_t)((t - 1) * 4 + g) * 1024;
      unsigned long long hv[4], cv[4];
#pragma unroll
      for (int v = 0; v < 4; ++v) {
        hv[v] = aload_u64(hp + v * 256 + tid);
        cv[v] = aload_u64(hcp + v * 256 + tid);
      }
      bool again = true;
      while (again) {
        again = false;
#pragma unroll
        for (int v = 0; v < 4; ++v) {
          if ((unsigned)hv[v] == SENTB || (unsigned)(hv[v] >> 32) == SENTB) {
            hv[v] = aload_u64(hp + v * 256 + tid); again = true;
          }
          if ((unsigned)cv[v] == SENTB || (unsigned)(cv[v] >> 32) == SENTB) {
            cv[v] = aload_u64(hcp + v * 256 + tid); again = true;
          }
        }
      }
#pragma unroll
      for (int v = 0; v < 4; ++v) {
        const int flat = v * 256 + tid, b = flat >> 7, k2 = flat & 127;
        union { unsigned long long u; float2 f; } H, C;
        H.u = hv[v]; C.u = cv[v];
        ((float2*)&h_s[b][0])[k2] = H.f;
        ((float2*)&hc_s[b][0])[k2] = C.f;
        const float tsb = ts_all[(g * 8 + b) * T_ + t];
        const float2 isg = ((const float2*)isig_s)[k2];
        float2* qrow = (float2*)&q_s[b][0];
        float2 q0 = make_float2(tsb * C.f.x, tsb * C.f.y);
        qrow[k2] = q0;
        qrow[128 + k2] = make_float2(tsb * tanh_f(C.f.x * isg.x),
                                     tsb * tanh_f(C.f.y * isg.y));
        qrow[256 + k2] = make_float2(tsb * q0.x, tsb * q0.y);
      }
    }
    __syncthreads();

    // ======== Stage B: matvecs + in-wave reductions ========
    float accg[2][8];
#pragma unroll
    for (int b = 0; b < 8; ++b) {
      const float4* h4p = (const float4*)&h_s[b][kq << 4];
      const float4 x0 = h4p[0], x1 = h4p[1], x2 = h4p[2], x3 = h4p[3];
#pragma unroll
      for (int c = 0; c < 2; ++c) {
        float s = wg[c][0] * x0.x;
        s = fmaf(wg[c][1],  x0.y, s); s = fmaf(wg[c][2],  x0.z, s);
        s = fmaf(wg[c][3],  x0.w, s); s = fmaf(wg[c][4],  x1.x, s);
        s = fmaf(wg[c][5],  x1.y, s); s = fmaf(wg[c][6],  x1.z, s);
        s = fmaf(wg[c][7],  x1.w, s); s = fmaf(wg[c][8],  x2.x, s);
        s = fmaf(wg[c][9],  x2.y, s); s = fmaf(wg[c][10], x2.z, s);
        s = fmaf(wg[c][11], x2.w, s); s = fmaf(wg[c][12], x3.x, s);
        s = fmaf(wg[c][13], x3.y, s); s = fmaf(wg[c][14], x3.z, s);
        s = fmaf(wg[c][15], x3.w, s);
        accg[c][b] = s;
      }
    }
    float accc[2][8];
#pragma unroll
    for (int r = 0; r < 2; ++r)
#pragma unroll
      for (int b = 0; b < 8; ++b) accc[r][b] = 0.f;
#pragma unroll
    for (int b = 0; b < 8; ++b) {
      const float2* q2p = (const float2*)&q_s[b][0];
#pragma unroll
      for (int j = 0; j < 6; ++j) {
        const float2 qv = q2p[kq6 + 64 * j];
#pragma unroll
        for (int r = 0; r < 2; ++r) {
          accc[r][b] = fmaf(wc[r][2 * j],     qv.x, accc[r][b]);
          accc[r][b] = fmaf(wc[r][2 * j + 1], qv.y, accc[r][b]);
        }
      }
    }
    // gates reduce over kq (lane bits 0..3)
#pragma unroll
    for (int c = 0; c < 2; ++c)
#pragma unroll
      for (int b = 0; b < 8; ++b) {
        float s = accg[c][b];
        s += __shfl_xor(s, 1); s += __shfl_xor(s, 2);
        s += __shfl_xor(s, 4); s += __shfl_xor(s, 8);
        accg[c][b] = s;
      }
    if (kq == 0) {
#pragma unroll
      for (int c = 0; c < 2; ++c)
#pragma unroll
        for (int b = 0; b < 8; ++b)
          gdot_s[(2 * cg + c) * 8 + b] = accg[c][b];
    }
    // cfc reduce over all 64 lanes
#pragma unroll
    for (int r = 0; r < 2; ++r)
#pragma unroll
      for (int b = 0; b < 8; ++b) {
        float s = accc[r][b];
        s += __shfl_xor(s, 1);  s += __shfl_xor(s, 2);
        s += __shfl_xor(s, 4);  s += __shfl_xor(s, 8);
        s += __shfl_xor(s, 16); s += __shfl_xor(s, 32);
        accc[r][b] = s;
      }
    if (kq6 == 0) {
#pragma unroll
      for (int r = 0; r < 2; ++r)
#pragma unroll
        for (int b = 0; b < 8; ++b)
          cfc_s[2 * wv + r][b] = accc[r][b];
    }
    __syncthreads();

    // ======== Stage C: elementwise + store (wave 0) ========
    if (tid < 64) {
      const int b = tid & 7, jj = tid >> 3;
      const float gi = gdot_s[tid]       + xg_s[tid];
      const float gf = gdot_s[64 + tid]  + xg_s[64 + tid];
      const float gg = gdot_s[128 + tid] + xg_s[128 + tid];
      const float go = gdot_s[192 + tid] + xg_s[192 + tid];
      const float i_ = sigm_f(gi), f_ = sigm_f(gf);
      const float g_ = tanh_f(gg), o_ = sigm_f(go);
      const float cn = fmaf(f_, cst_s[tid], i_ * g_);
      cst_s[tid] = cn;
      const float ht = o_ * tanh_f(cn);
      const float dot = cfc_s[jj][b];
      const float hcold = hc_s[b][8 * cb + jj];
      const float tsb = ts_s[b];
      const float hn = hcold + dot + tsb * bxv * itau_comb + ht;
      const int col = 8 * cb + jj;
      astore_f(hseq  + (size_t)(t * 4 + g) * 2048 + b * 256 + col, ht);
      astore_f(hcseq + (size_t)(t * 4 + g) * 2048 + b * 256 + col, hn);
    }
    __syncthreads();
  }
}

// ---------------- y = hc @ W_C^T + b_C (reads hcseq layout [t][g][b][256]) ----------------
__global__ __launch_bounds__(256) void out_kernel(
    const float* __restrict__ hc, const float* __restrict__ WCT,
    const float* __restrict__ bC, float* __restrict__ y) {
  __shared__ float hs[16 * 256];
  const int tid = threadIdx.x;
#pragma unroll
  for (int v = 0; v < 4; ++v) {
    const int flat = v * 256 + tid;        // float4 index in 16x256
    const int r = flat >> 6, f4 = flat & 63;
    const int row = blockIdx.x * 16 + r;   // = b*128 + t
    const int b = row >> 7, t = row & 127;
    ((float4*)hs)[flat] = ((const float4*)(hc + (size_t)(t * 32 + b) * 256))[f4];
  }
  __syncthreads();
  const int r = tid >> 4, cgg = tid & 15;
  const int c0 = cgg * 8;
  const float4* b4 = (const float4*)(bC + c0);
  float4 bA = b4[0], bB = b4[1];
  float a0 = bA.x, a1 = bA.y, a2 = bA.z, a3 = bA.w;
  float a4 = bB.x, a5 = bB.y, a6 = bB.z, a7 = bB.w;
  const float4* hr4 = (const float4*)(hs + r * 256);
#pragma unroll 4
  for (int k4 = 0; k4 < 64; ++k4) {
    float4 hv = hr4[k4];
#define STEPD(kk, comp)                                                     \
    {                                                                       \
      const float4* w = (const float4*)(WCT + (k4 * 4 + kk) * 128 + c0);    \
      float4 wA = w[0], wB = w[1];                                          \
      a0 = fmaf(wA.x, comp, a0); a1 = fmaf(wA.y, comp, a1);                 \
      a2 = fmaf(wA.z, comp, a2); a3 = fmaf(wA.w, comp, a3);                 \
      a4 = fmaf(wB.x, comp, a4); a5 = fmaf(wB.y, comp, a5);                 \
      a6 = fmaf(wB.z, comp, a6); a7 = fmaf(wB.w, comp, a7);                 \
    }
    STEPD(0, hv.x) STEPD(1, hv.y) STEPD(2, hv.z) STEPD(3, hv.w)
#undef STEPD
  }
  const int row = blockIdx.x * 16 + r;
  float4* dst = (float4*)(y + (size_t)row * 128 + c0);
  dst[0] = make_float4(a0, a1, a2, a3);
  dst[1] = make_float4(a4, a5, a6, a7);
}

extern "C" void kernel_launch(void* const* d_in, const int* in_sizes, int n_in,
                              void* d_out, int out_size, void* d_ws, size_t ws_size,
                              hipStream_t stream) {
  const float* x     = (const float*)d_in[0];
  const float* tspan = (const float*)d_in[1];
  const float* tau   = (const float*)d_in[2];
  const float* sigma = (const float*)d_in[3];
  const float* W_A   = (const float*)d_in[4];
  const float* W_B   = (const float*)d_in[5];
  const float* b_B   = (const float*)d_in[6];
  const float* W_C   = (const float*)d_in[7];
  const float* b_C   = (const float*)d_in[8];
  const float* W_ih  = (const float*)d_in[9];
  const float* W_hh  = (const float*)d_in[10];
  const float* b_ih  = (const float*)d_in[11];
  const float* b_hh  = (const float*)d_in[12];
  float* ws = (float*)d_ws;
  float* y = (float*)d_out;

  // 163840+1280+32768 = 197888 normal + 1048576 sentinel u64 = 1246464 threads
  pack_kernel<<<4870, 256, 0, stream>>>(W_ih, W_B, b_ih, b_hh, b_B, W_C, ws);
  m2_kernel<<<256, 256, 0, stream>>>(W_A, tau, ws + OFF_M2);
  xgt_kernel<<<dim3(512, 5), 256, 0, stream>>>(x, ws + OFF_WCOMBT, ws + OFF_BIAS,
                                               ws + OFF_XG2, ws + OFF_BX2);
  recur3_kernel<<<128, 256, 0, stream>>>(
      tspan, tau, sigma, W_hh, W_A, ws + OFF_M2, ws + OFF_XG2, ws + OFF_BX2,
      ws + OFF_HSEQ, ws + OFF_HCSEQ);
  out_kernel<<<256, 256, 0, stream>>>(ws + OFF_HCSEQ, ws + OFF_WCT, b_C, y);
}